// Round 1
// baseline (387.325 us; speedup 1.0000x reference)
//
#include <hip/hip_runtime.h>
#include <stdint.h>

// Problem constants: B=4, S=4096, E=256
#define SEQ   4096
#define EMB   256
#define NROW  16384   // B*S

typedef short s16x8 __attribute__((ext_vector_type(8)));
typedef float f32x4 __attribute__((ext_vector_type(4)));

#define LOG2E 1.44269504088896340736f

__device__ __forceinline__ unsigned short f2bf(float f) {
    unsigned int u = __builtin_bit_cast(unsigned int, f);
    u += 0x7FFFu + ((u >> 16) & 1u);   // RNE
    return (unsigned short)(u >> 16);
}

// Barrier with LDS-visibility fence but NO vmcnt drain (keeps global prefetch in flight).
__device__ __forceinline__ void fence_barrier() {
    __asm__ volatile("s_waitcnt lgkmcnt(0)" ::: "memory");
    __builtin_amdgcn_s_barrier();
    __asm__ volatile("" ::: "memory");
}

// ---------------------------------------------------------------------------
// Kernel 1: QKV projection.  y = x @ W^T  (W stored [out,in], both rows contiguous)
// Writes Qb (scaled by 1/16) bf16 [16384][256], Kb bf16 [16384][256],
// Vt bf16 [b][d][s] (transposed for contiguous PV B-fragment reads).
// Grid: 256 blocks = 4 col-tiles x 64 row-groups; each block does 4 row-tiles of 64.
// ---------------------------------------------------------------------------
#define WSTR 264   // padded LDS stride (elems); 264*2=528B: 16B-aligned rows, 2-way banks

__global__ __launch_bounds__(256, 1) void proj_kernel(
    const float* __restrict__ x,  const float* __restrict__ Wq,
    const float* __restrict__ Wk, const float* __restrict__ Wv,
    unsigned short* __restrict__ Qb, unsigned short* __restrict__ Kb,
    unsigned short* __restrict__ Vt)
{
    __shared__ unsigned short Wl[3][64][WSTR];   // ~101 KB
    const int bid = blockIdx.x;
    const int ct  = bid & 3;    // out-col tile (64 cols of 256)
    const int rb  = bid >> 2;   // row group (4 tiles of 64 rows)
    const int t   = threadIdx.x;

    // stage 64x256 chunk of each W as bf16 into padded LDS
    {
        const float* Ws[3] = {Wq, Wk, Wv};
        const int o = t >> 2, seg = t & 3;   // 4 threads per W-row
        for (int w = 0; w < 3; ++w) {
            const float* src = Ws[w] + (ct*64 + o)*256 + seg*64;
            #pragma unroll
            for (int i = 0; i < 16; ++i) {
                float4 v = *(const float4*)(src + i*4);
                ushort4 bv;
                bv.x = f2bf(v.x); bv.y = f2bf(v.y); bv.z = f2bf(v.z); bv.w = f2bf(v.w);
                *(ushort4*)&Wl[w][o][seg*64 + i*4] = bv;
            }
        }
    }
    __syncthreads();

    const int wave = t >> 6, lane = t & 63;
    const int g = lane >> 4, lr = lane & 15;

    for (int it = 0; it < 4; ++it) {
        const int rowbase = (rb*4 + it)*64 + wave*16;
        // A fragments from x (fp32 -> bf16): row = lr, k = g*8+j within 32-chunk
        s16x8 a[8];
        {
            const float* xr = x + (rowbase + lr)*256;
            #pragma unroll
            for (int c = 0; c < 8; ++c) {
                const float* p = xr + c*32 + g*8;
                float4 v0 = *(const float4*)(p);
                float4 v1 = *(const float4*)(p + 4);
                union { unsigned short u[8]; s16x8 v; } tmp;
                tmp.u[0]=f2bf(v0.x); tmp.u[1]=f2bf(v0.y); tmp.u[2]=f2bf(v0.z); tmp.u[3]=f2bf(v0.w);
                tmp.u[4]=f2bf(v1.x); tmp.u[5]=f2bf(v1.y); tmp.u[6]=f2bf(v1.z); tmp.u[7]=f2bf(v1.w);
                a[c] = tmp.v;
            }
        }
        f32x4 acc[3][4];
        #pragma unroll
        for (int w = 0; w < 3; ++w)
            #pragma unroll
            for (int cf = 0; cf < 4; ++cf)
                #pragma unroll
                for (int j = 0; j < 4; ++j) acc[w][cf][j] = 0.0f;

        #pragma unroll
        for (int w = 0; w < 3; ++w)
            #pragma unroll
            for (int cf = 0; cf < 4; ++cf)
                #pragma unroll
                for (int c = 0; c < 8; ++c) {
                    s16x8 bfr = *(const s16x8*)&Wl[w][cf*16 + lr][c*32 + g*8];
                    acc[w][cf] = __builtin_amdgcn_mfma_f32_16x16x32_bf16(a[c], bfr, acc[w][cf], 0, 0, 0);
                }

        // epilogue: C layout row = g*4+j, col = lr (+16*cf)
        #pragma unroll
        for (int cf = 0; cf < 4; ++cf) {
            const int col = ct*64 + cf*16 + lr;
            #pragma unroll
            for (int j = 0; j < 4; ++j) {
                const int srow = rowbase + g*4 + j;
                Qb[srow*256 + col] = f2bf(acc[0][cf][j] * 0.0625f);  // fold 1/sqrt(256)
                Kb[srow*256 + col] = f2bf(acc[1][cf][j]);
                const int bb = srow >> 12, ss = srow & 4095;
                Vt[(bb*256 + col)*4096 + ss] = f2bf(acc[2][cf][j]);
            }
        }
    }
}

// ---------------------------------------------------------------------------
// Kernel 2: flash attention.  256 blocks = (b, q-tile of 64). 4 waves x 16 q-rows.
// KVBLK=32, double-buffered K[32][264] and Vt[256][40] LDS tiles, reg-staged
// (issue loads early, ds_write next iter), one lgkm-only barrier per tile.
// ---------------------------------------------------------------------------
#define KVB  32
#define NT   128         // 4096/32
#define KSTR 264
#define VSTR 40
#define PSTR 40

__global__ __launch_bounds__(256, 1) void attn_kernel(
    const unsigned short* __restrict__ Qb, const unsigned short* __restrict__ Kb,
    const unsigned short* __restrict__ Vt, float* __restrict__ out)
{
    __shared__ unsigned short Kl[2][KVB][KSTR];   // 33.8 KB
    __shared__ unsigned short Vl[2][EMB][VSTR];   // 40.0 KB
    __shared__ unsigned short Pl[4][16][PSTR];    //  5.1 KB (wave-private)

    const int bid = blockIdx.x;
    const int b   = bid >> 6;
    const int qt  = bid & 63;
    const int t   = threadIdx.x;
    const int wave = t >> 6, lane = t & 63;
    const int g = lane >> 4, lr = lane & 15;

    // Q A-fragments (already scaled by 1/16)
    s16x8 qa[8];
    {
        const unsigned short* qp = Qb + (b*4096 + qt*64 + wave*16 + lr)*256;
        #pragma unroll
        for (int c = 0; c < 8; ++c)
            qa[c] = *(const s16x8*)(qp + c*32 + g*8);
    }

    f32x4 acc[16];
    #pragma unroll
    for (int c = 0; c < 16; ++c)
        #pragma unroll
        for (int j = 0; j < 4; ++j) acc[c][j] = 0.0f;
    float m[4], l[4];
    #pragma unroll
    for (int j = 0; j < 4; ++j) { m[j] = -__builtin_inff(); l[j] = 0.0f; }

    const unsigned short* Kg = Kb + b*4096*256;
    const unsigned short* Vg = Vt + b*256*4096;

    // prologue: load tile 0 into regs
    s16x8 kreg[4], vreg[4];
    #pragma unroll
    for (int i = 0; i < 4; ++i) {
        const int idx = i*256 + t;
        const int kv = idx >> 5, e8 = idx & 31;     // K: 32 rows x 32 granules
        kreg[i] = *(const s16x8*)(Kg + kv*256 + e8*8);
        const int d = idx >> 2, seg = idx & 3;      // Vt: 256 rows x 4 granules
        vreg[i] = *(const s16x8*)(Vg + d*4096 + seg*8);
    }

    for (int kt = 0; kt < NT; ++kt) {
        const int buf = kt & 1;
        // write staged tile kt into LDS[buf] (vmcnt wait lands here, loads long arrived)
        #pragma unroll
        for (int i = 0; i < 4; ++i) {
            const int idx = i*256 + t;
            const int kv = idx >> 5, e8 = idx & 31;
            *(s16x8*)&Kl[buf][kv][e8*8] = kreg[i];
            const int d = idx >> 2, seg = idx & 3;
            *(s16x8*)&Vl[buf][d][seg*8] = vreg[i];
        }
        // issue global loads for tile kt+1 (consumed next iter -> hidden under compute)
        if (kt + 1 < NT) {
            const int kv0 = (kt + 1) * KVB;
            #pragma unroll
            for (int i = 0; i < 4; ++i) {
                const int idx = i*256 + t;
                const int kv = idx >> 5, e8 = idx & 31;
                kreg[i] = *(const s16x8*)(Kg + (kv0 + kv)*256 + e8*8);
                const int d = idx >> 2, seg = idx & 3;
                vreg[i] = *(const s16x8*)(Vg + d*4096 + kv0 + seg*8);
            }
        }
        fence_barrier();

        // QK^T: S[16q x 32kv], A=Q chunk, B-frag reads K rows contiguously
        f32x4 sc[2];
        #pragma unroll
        for (int f = 0; f < 2; ++f)
            #pragma unroll
            for (int j = 0; j < 4; ++j) sc[f][j] = 0.0f;
        #pragma unroll
        for (int f = 0; f < 2; ++f)
            #pragma unroll
            for (int c = 0; c < 8; ++c) {
                s16x8 kb = *(const s16x8*)&Kl[buf][f*16 + lr][c*32 + g*8];
                sc[f] = __builtin_amdgcn_mfma_f32_16x16x32_bf16(qa[c], kb, sc[f], 0, 0, 0);
            }

        // online softmax: row r = g*4+j lives in 16 lanes of group g (col = lane&15)
        float mt[4];
        #pragma unroll
        for (int j = 0; j < 4; ++j) mt[j] = fmaxf(sc[0][j], sc[1][j]);
        #pragma unroll
        for (int mask = 1; mask <= 8; mask <<= 1)
            #pragma unroll
            for (int j = 0; j < 4; ++j)
                mt[j] = fmaxf(mt[j], __shfl_xor(mt[j], mask));

        float al[4], pr[2][4], ps[4];
        #pragma unroll
        for (int j = 0; j < 4; ++j) {
            const float mn = fmaxf(m[j], mt[j]);
            al[j] = __builtin_amdgcn_exp2f((m[j] - mn) * LOG2E);  // 0 on first tile
            m[j] = mn;
            pr[0][j] = __builtin_amdgcn_exp2f((sc[0][j] - mn) * LOG2E);
            pr[1][j] = __builtin_amdgcn_exp2f((sc[1][j] - mn) * LOG2E);
            ps[j] = pr[0][j] + pr[1][j];
        }
        #pragma unroll
        for (int mask = 1; mask <= 8; mask <<= 1)
            #pragma unroll
            for (int j = 0; j < 4; ++j)
                ps[j] += __shfl_xor(ps[j], mask);
        #pragma unroll
        for (int j = 0; j < 4; ++j) l[j] = l[j] * al[j] + ps[j];
        #pragma unroll
        for (int c = 0; c < 16; ++c)
            #pragma unroll
            for (int j = 0; j < 4; ++j) acc[c][j] *= al[j];

        // P: C-layout -> wave-private LDS -> A-fragment (in-order DS within wave)
        #pragma unroll
        for (int f = 0; f < 2; ++f)
            #pragma unroll
            for (int j = 0; j < 4; ++j)
                Pl[wave][g*4 + j][f*16 + lr] = f2bf(pr[f][j]);
        s16x8 pa = *(const s16x8*)&Pl[wave][lr][g*8];

        // PV: out[16q x 256d] += P[16x32] * V[32 x d16-chunk]; B-frag = Vt rows contiguous
        #pragma unroll
        for (int c = 0; c < 16; ++c) {
            s16x8 vb = *(const s16x8*)&Vl[buf][c*16 + lr][g*8];
            acc[c] = __builtin_amdgcn_mfma_f32_16x16x32_bf16(pa, vb, acc[c], 0, 0, 0);
        }
    }

    // epilogue: out fp32 [b][s][d]
    float inv[4];
    #pragma unroll
    for (int j = 0; j < 4; ++j) inv[j] = 1.0f / l[j];
    float* op = out + (b*4096 + qt*64 + wave*16)*256;
    #pragma unroll
    for (int c = 0; c < 16; ++c)
        #pragma unroll
        for (int j = 0; j < 4; ++j)
            op[(g*4 + j)*256 + c*16 + lr] = acc[c][j] * inv[j];
}

// ---------------------------------------------------------------------------
extern "C" void kernel_launch(void* const* d_in, const int* in_sizes, int n_in,
                              void* d_out, int out_size, void* d_ws, size_t ws_size,
                              hipStream_t stream) {
    const float* x  = (const float*)d_in[0];
    const float* Wq = (const float*)d_in[1];
    const float* Wk = (const float*)d_in[2];
    const float* Wv = (const float*)d_in[3];

    unsigned short* Qb = (unsigned short*)d_ws;          // 16384*256 bf16
    unsigned short* Kb = Qb + NROW*EMB;                  // 16384*256 bf16
    unsigned short* Vt = Kb + NROW*EMB;                  // [b][d][s] bf16

    proj_kernel<<<256, 256, 0, stream>>>(x, Wq, Wk, Wv, Qb, Kb, Vt);
    attn_kernel<<<256, 256, 0, stream>>>(Qb, Kb, Vt, (float*)d_out);
}

// Round 3
// 302.737 us; speedup vs baseline: 1.2794x; 1.2794x over previous
//
#include <hip/hip_runtime.h>
#include <stdint.h>

// Problem constants: B=4, S=4096, E=256
#define SEQ   4096
#define EMB   256
#define NROW  16384   // B*S

typedef short s16x8 __attribute__((ext_vector_type(8)));
typedef float f32x4 __attribute__((ext_vector_type(4)));

#define LOG2E 1.44269504088896340736f

__device__ __forceinline__ unsigned short f2bf(float f) {
    unsigned int u = __builtin_bit_cast(unsigned int, f);
    u += 0x7FFFu + ((u >> 16) & 1u);   // RNE
    return (unsigned short)(u >> 16);
}

// Barrier with LDS-visibility fence but NO vmcnt drain (keeps global prefetch in flight).
__device__ __forceinline__ void fence_barrier() {
    __asm__ volatile("s_waitcnt lgkmcnt(0)" ::: "memory");
    __builtin_amdgcn_s_barrier();
    __asm__ volatile("" ::: "memory");
}

// ---------------------------------------------------------------------------
// Kernel 1: QKV projection.  y = x @ W^T.
// Qb (scaled 1/16) bf16 [16384][256], Kb bf16 [16384][256],
// Vt bf16 [b][d][s] -- transposed via LDS so global stores are 16B coalesced.
// ---------------------------------------------------------------------------
#define WSTR 264

__global__ __launch_bounds__(256, 1) void proj_kernel(
    const float* __restrict__ x,  const float* __restrict__ Wq,
    const float* __restrict__ Wk, const float* __restrict__ Wv,
    unsigned short* __restrict__ Qb, unsigned short* __restrict__ Kb,
    unsigned short* __restrict__ Vt)
{
    __shared__ unsigned short Wl[3][64][WSTR];   // ~101 KB
    __shared__ unsigned short Vtr[64][72];       // 9 KB transpose staging
    const int bid = blockIdx.x;
    const int ct  = bid & 3;    // out-col tile (64 cols of 256)
    const int rb  = bid >> 2;   // row group (4 tiles of 64 rows)
    const int t   = threadIdx.x;

    {   // stage 64x256 chunk of each W as bf16
        const float* Ws[3] = {Wq, Wk, Wv};
        const int o = t >> 2, seg = t & 3;
        for (int w = 0; w < 3; ++w) {
            const float* src = Ws[w] + (ct*64 + o)*256 + seg*64;
            #pragma unroll
            for (int i = 0; i < 16; ++i) {
                float4 v = *(const float4*)(src + i*4);
                ushort4 bv;
                bv.x = f2bf(v.x); bv.y = f2bf(v.y); bv.z = f2bf(v.z); bv.w = f2bf(v.w);
                *(ushort4*)&Wl[w][o][seg*64 + i*4] = bv;
            }
        }
    }
    __syncthreads();

    const int wave = t >> 6, lane = t & 63;
    const int g = lane >> 4, lr = lane & 15;

    for (int it = 0; it < 4; ++it) {
        const int rowblk = (rb*4 + it)*64;
        const int rowbase = rowblk + wave*16;
        s16x8 a[8];
        {
            const float* xr = x + (rowbase + lr)*256;
            #pragma unroll
            for (int c = 0; c < 8; ++c) {
                const float* p = xr + c*32 + g*8;
                float4 v0 = *(const float4*)(p);
                float4 v1 = *(const float4*)(p + 4);
                union { unsigned short u[8]; s16x8 v; } tmp;
                tmp.u[0]=f2bf(v0.x); tmp.u[1]=f2bf(v0.y); tmp.u[2]=f2bf(v0.z); tmp.u[3]=f2bf(v0.w);
                tmp.u[4]=f2bf(v1.x); tmp.u[5]=f2bf(v1.y); tmp.u[6]=f2bf(v1.z); tmp.u[7]=f2bf(v1.w);
                a[c] = tmp.v;
            }
        }
        f32x4 acc[3][4];
        #pragma unroll
        for (int w = 0; w < 3; ++w)
            #pragma unroll
            for (int cf = 0; cf < 4; ++cf)
                #pragma unroll
                for (int j = 0; j < 4; ++j) acc[w][cf][j] = 0.0f;

        #pragma unroll
        for (int w = 0; w < 3; ++w)
            #pragma unroll
            for (int cf = 0; cf < 4; ++cf)
                #pragma unroll
                for (int c = 0; c < 8; ++c) {
                    s16x8 bfr = *(const s16x8*)&Wl[w][cf*16 + lr][c*32 + g*8];
                    acc[w][cf] = __builtin_amdgcn_mfma_f32_16x16x32_bf16(a[c], bfr, acc[w][cf], 0, 0, 0);
                }

        // Q,K direct; V via LDS transpose
        #pragma unroll
        for (int cf = 0; cf < 4; ++cf) {
            const int col = ct*64 + cf*16 + lr;
            #pragma unroll
            for (int j = 0; j < 4; ++j) {
                const int srow = rowbase + g*4 + j;
                Qb[srow*256 + col] = f2bf(acc[0][cf][j] * 0.0625f);  // fold 1/sqrt(256)
                Kb[srow*256 + col] = f2bf(acc[1][cf][j]);
            }
        }
        __syncthreads();   // previous iteration's Vtr reads done
        #pragma unroll
        for (int cf = 0; cf < 4; ++cf) {
            ushort4 pv;
            pv.x = f2bf(acc[2][cf][0]); pv.y = f2bf(acc[2][cf][1]);
            pv.z = f2bf(acc[2][cf][2]); pv.w = f2bf(acc[2][cf][3]);
            *(ushort4*)&Vtr[cf*16 + lr][wave*16 + g*4] = pv;
        }
        __syncthreads();
        {
            const int colL = t >> 2, seg = t & 3;
            const int bb = rowblk >> 12, ss0 = rowblk & 4095;
            unsigned short* dst = Vt + ((size_t)(bb*256 + ct*64 + colL))*4096 + ss0 + seg*16;
            *(s16x8*)(dst)     = *(const s16x8*)&Vtr[colL][seg*16];
            *(s16x8*)(dst + 8) = *(const s16x8*)&Vtr[colL][seg*16 + 8];
        }
    }
}

// ---------------------------------------------------------------------------
// Kernel 2: flash attention, split-KV H=2.  Grid 512 = 8 (b,h) groups x 64 q-tiles.
// bid&7 = (b,h) group -> pinned to one XCD (default bid%8 round-robin), so each
// XCD's L2 holds one 1MB K-chunk + 1MB V-chunk.
// 4 waves x 16 q-rows; KVB=32, double-buffered PADDED K/V LDS tiles (round-1
// proven addressing), reg-staged prefetch, one lgkm-only barrier per tile.
// LDS = 79872 B -> exactly 2 blocks/CU (159744 <= 163840).
// h=0 partials to ws, h=1 partials to d_out; combine kernel merges.
// ---------------------------------------------------------------------------
#define KVB  32
#define NT   64          // 2048/32 per half
#define KSTR 264
#define VSTR 40
#define PSTR 40
#define RESCALE_THR 8.0f

__global__ __launch_bounds__(256, 2) void attn_kernel(
    const unsigned short* __restrict__ Qb, const unsigned short* __restrict__ Kb,
    const unsigned short* __restrict__ Vt, float* __restrict__ pacc0,
    float* __restrict__ pm, float* __restrict__ pl, float* __restrict__ out)
{
    __shared__ unsigned short Kl[2][KVB][KSTR];   // 33792 B
    __shared__ unsigned short Vl[2][EMB][VSTR];   // 40960 B
    __shared__ unsigned short Pl[4][16][PSTR];    //  5120 B (wave-private)

    const int bid = blockIdx.x;
    const int grp = bid & 7;
    const int b = grp >> 1, h = grp & 1;
    const int qt  = bid >> 3;
    const int t   = threadIdx.x;
    const int wave = t >> 6, lane = t & 63;
    const int g = lane >> 4, lr = lane & 15;
    const int kv0 = h * 2048;

    s16x8 qa[8];
    {
        const unsigned short* qp = Qb + (b*4096 + qt*64 + wave*16 + lr)*256;
        #pragma unroll
        for (int c = 0; c < 8; ++c)
            qa[c] = *(const s16x8*)(qp + c*32 + g*8);
    }

    f32x4 acc[16];
    #pragma unroll
    for (int c = 0; c < 16; ++c)
        #pragma unroll
        for (int j = 0; j < 4; ++j) acc[c][j] = 0.0f;
    float m[4], l[4];
    #pragma unroll
    for (int j = 0; j < 4; ++j) { m[j] = -__builtin_inff(); l[j] = 0.0f; }

    const unsigned short* Kg = Kb + b*4096*256;
    const unsigned short* Vg = Vt + b*256*4096;

    s16x8 kreg[4], vreg[4];
    #pragma unroll
    for (int i = 0; i < 4; ++i) {
        const int idx = i*256 + t;
        const int kv = idx >> 5, e8 = idx & 31;     // K: 32 rows x 32 granules
        kreg[i] = *(const s16x8*)(Kg + (kv0 + kv)*256 + e8*8);
        const int d = idx >> 2, seg = idx & 3;      // Vt: 256 rows x 4 granules
        vreg[i] = *(const s16x8*)(Vg + d*4096 + kv0 + seg*8);
    }

    for (int kt = 0; kt < NT; ++kt) {
        const int buf = kt & 1;
        #pragma unroll
        for (int i = 0; i < 4; ++i) {
            const int idx = i*256 + t;
            const int kv = idx >> 5, e8 = idx & 31;
            *(s16x8*)&Kl[buf][kv][e8*8] = kreg[i];
            const int d = idx >> 2, seg = idx & 3;
            *(s16x8*)&Vl[buf][d][seg*8] = vreg[i];
        }
        if (kt + 1 < NT) {
            const int kvn = kv0 + (kt + 1) * KVB;
            #pragma unroll
            for (int i = 0; i < 4; ++i) {
                const int idx = i*256 + t;
                const int kv = idx >> 5, e8 = idx & 31;
                kreg[i] = *(const s16x8*)(Kg + (kvn + kv)*256 + e8*8);
                const int d = idx >> 2, seg = idx & 3;
                vreg[i] = *(const s16x8*)(Vg + d*4096 + kvn + seg*8);
            }
        }
        fence_barrier();

        // QK^T
        f32x4 sc[2];
        #pragma unroll
        for (int f = 0; f < 2; ++f)
            #pragma unroll
            for (int j = 0; j < 4; ++j) sc[f][j] = 0.0f;
        __builtin_amdgcn_s_setprio(1);
        #pragma unroll
        for (int f = 0; f < 2; ++f)
            #pragma unroll
            for (int c = 0; c < 8; ++c) {
                s16x8 kb = *(const s16x8*)&Kl[buf][f*16 + lr][c*32 + g*8];
                sc[f] = __builtin_amdgcn_mfma_f32_16x16x32_bf16(qa[c], kb, sc[f], 0, 0, 0);
            }
        __builtin_amdgcn_s_setprio(0);

        // online softmax (row r = g*4+j spread over the 16 lanes of group g)
        float mt[4];
        #pragma unroll
        for (int j = 0; j < 4; ++j) mt[j] = fmaxf(sc[0][j], sc[1][j]);
        #pragma unroll
        for (int mask = 1; mask <= 8; mask <<= 1)
            #pragma unroll
            for (int j = 0; j < 4; ++j)
                mt[j] = fmaxf(mt[j], __shfl_xor(mt[j], mask));

        const float dd = fmaxf(fmaxf(mt[0]-m[0], mt[1]-m[1]), fmaxf(mt[2]-m[2], mt[3]-m[3]));
        float pr[2][4];
        if (__all(dd <= RESCALE_THR)) {
            // defer-max: keep stale m, P bounded by e^8, skip acc rescale
            float ps[4];
            #pragma unroll
            for (int j = 0; j < 4; ++j) {
                pr[0][j] = __builtin_amdgcn_exp2f((sc[0][j] - m[j]) * LOG2E);
                pr[1][j] = __builtin_amdgcn_exp2f((sc[1][j] - m[j]) * LOG2E);
                ps[j] = pr[0][j] + pr[1][j];
            }
            #pragma unroll
            for (int mask = 1; mask <= 8; mask <<= 1)
                #pragma unroll
                for (int j = 0; j < 4; ++j)
                    ps[j] += __shfl_xor(ps[j], mask);
            #pragma unroll
            for (int j = 0; j < 4; ++j) l[j] += ps[j];
        } else {
            float ps[4], al[4];
            #pragma unroll
            for (int j = 0; j < 4; ++j) {
                const float mn = fmaxf(m[j], mt[j]);
                al[j] = __builtin_amdgcn_exp2f((m[j] - mn) * LOG2E);
                m[j] = mn;
                pr[0][j] = __builtin_amdgcn_exp2f((sc[0][j] - mn) * LOG2E);
                pr[1][j] = __builtin_amdgcn_exp2f((sc[1][j] - mn) * LOG2E);
                ps[j] = pr[0][j] + pr[1][j];
            }
            #pragma unroll
            for (int mask = 1; mask <= 8; mask <<= 1)
                #pragma unroll
                for (int j = 0; j < 4; ++j)
                    ps[j] += __shfl_xor(ps[j], mask);
            #pragma unroll
            for (int j = 0; j < 4; ++j) l[j] = l[j] * al[j] + ps[j];
            #pragma unroll
            for (int c = 0; c < 16; ++c)
                #pragma unroll
                for (int j = 0; j < 4; ++j) acc[c][j] *= al[j];
        }

        // P transpose: C-layout -> A-fragment via wave-private LDS
        #pragma unroll
        for (int f = 0; f < 2; ++f)
            #pragma unroll
            for (int j = 0; j < 4; ++j)
                Pl[wave][g*4 + j][f*16 + lr] = f2bf(pr[f][j]);
        s16x8 pa = *(const s16x8*)&Pl[wave][lr][g*8];

        __builtin_amdgcn_s_setprio(1);
        #pragma unroll
        for (int c = 0; c < 16; ++c) {
            s16x8 vb = *(const s16x8*)&Vl[buf][c*16 + lr][g*8];
            acc[c] = __builtin_amdgcn_mfma_f32_16x16x32_bf16(pa, vb, acc[c], 0, 0, 0);
        }
        __builtin_amdgcn_s_setprio(0);
    }

    // epilogue: unnormalized partials + (m,l)
    float* dst = h ? out : pacc0;
    const int rowbase = b*4096 + qt*64 + wave*16;
    #pragma unroll
    for (int c = 0; c < 16; ++c)
        #pragma unroll
        for (int j = 0; j < 4; ++j)
            dst[(size_t)(rowbase + g*4 + j)*256 + c*16 + lr] = acc[c][j];
    if (lr == 0) {
        #pragma unroll
        for (int j = 0; j < 4; ++j) {
            const int r = rowbase + g*4 + j;
            pm[h*NROW + r] = m[j];
            pl[h*NROW + r] = l[j];
        }
    }
}

// ---------------------------------------------------------------------------
// Kernel 3: combine the two KV-half partials.  out = (a0*w0 + a1*w1)/(l0*w0+l1*w1)
// ---------------------------------------------------------------------------
__global__ __launch_bounds__(256, 4) void combine_kernel(
    const float* __restrict__ pacc0, const float* __restrict__ pm,
    const float* __restrict__ pl, float* __restrict__ out)
{
    const int idx = blockIdx.x*256 + threadIdx.x;   // 1,048,576 threads x float4
    const int row = idx >> 6, d4 = (idx & 63) << 2;
    const float m0 = pm[row], m1 = pm[NROW + row];
    const float l0 = pl[row], l1 = pl[NROW + row];
    const float M = fmaxf(m0, m1);
    const float w0 = __builtin_amdgcn_exp2f((m0 - M) * LOG2E);
    const float w1 = __builtin_amdgcn_exp2f((m1 - M) * LOG2E);
    const float r = 1.0f / (l0*w0 + l1*w1);
    const float4 a0 = *(const float4*)(pacc0 + (size_t)row*256 + d4);
    float4 a1 = *(const float4*)(out + (size_t)row*256 + d4);
    a1.x = (a0.x*w0 + a1.x*w1) * r;
    a1.y = (a0.y*w0 + a1.y*w1) * r;
    a1.z = (a0.z*w0 + a1.z*w1) * r;
    a1.w = (a0.w*w0 + a1.w*w1) * r;
    *(float4*)(out + (size_t)row*256 + d4) = a1;
}

// ---------------------------------------------------------------------------
extern "C" void kernel_launch(void* const* d_in, const int* in_sizes, int n_in,
                              void* d_out, int out_size, void* d_ws, size_t ws_size,
                              hipStream_t stream) {
    const float* x  = (const float*)d_in[0];
    const float* Wq = (const float*)d_in[1];
    const float* Wk = (const float*)d_in[2];
    const float* Wv = (const float*)d_in[3];

    unsigned short* Qb = (unsigned short*)d_ws;          // 8 MB
    unsigned short* Kb = Qb + NROW*EMB;                  // 8 MB
    unsigned short* Vt = Kb + NROW*EMB;                  // 8 MB, [b][d][s]
    float* pacc0 = (float*)(Vt + NROW*EMB);              // 16 MB
    float* pm    = pacc0 + (size_t)NROW*EMB;             // 128 KB (2 halves)
    float* pl    = pm + 2*NROW;                          // 128 KB
    // total ws use: ~40.3 MB

    proj_kernel<<<256, 256, 0, stream>>>(x, Wq, Wk, Wv, Qb, Kb, Vt);
    attn_kernel<<<512, 256, 0, stream>>>(Qb, Kb, Vt, pacc0, pm, pl, (float*)d_out);
    combine_kernel<<<4096, 256, 0, stream>>>(pacc0, pm, pl, (float*)d_out);
}

// Round 4
// 212.129 us; speedup vs baseline: 1.8259x; 1.4271x over previous
//
#include <hip/hip_runtime.h>
#include <stdint.h>

// Problem constants: B=4, S=4096, E=256
#define SEQ   4096
#define EMB   256
#define NROW  16384   // B*S

typedef short s16x8 __attribute__((ext_vector_type(8)));
typedef float f32x4 __attribute__((ext_vector_type(4)));

#define LOG2E 1.44269504088896340736f

__device__ __forceinline__ unsigned short f2bf(float f) {
    unsigned int u = __builtin_bit_cast(unsigned int, f);
    u += 0x7FFFu + ((u >> 16) & 1u);   // RNE
    return (unsigned short)(u >> 16);
}

// Barrier with LDS-visibility fence but NO vmcnt drain (keeps global prefetch in flight).
__device__ __forceinline__ void fence_barrier() {
    __asm__ volatile("s_waitcnt lgkmcnt(0)" ::: "memory");
    __builtin_amdgcn_s_barrier();
    __asm__ volatile("" ::: "memory");
}

// ---------------------------------------------------------------------------
// Kernel 0: x fp32 -> bf16 (done once; lets proj load A-frags as b128, no cvt)
// 4,194,304 elems / 8 per thread = 2048 blocks x 256
// ---------------------------------------------------------------------------
__global__ __launch_bounds__(256, 8) void xcvt_kernel(
    const float* __restrict__ x, unsigned short* __restrict__ xb)
{
    const size_t i = (size_t)(blockIdx.x*256 + threadIdx.x) * 8;
    const float4 v0 = *(const float4*)(x + i);
    const float4 v1 = *(const float4*)(x + i + 4);
    union { unsigned short u[8]; s16x8 v; } o;
    o.u[0]=f2bf(v0.x); o.u[1]=f2bf(v0.y); o.u[2]=f2bf(v0.z); o.u[3]=f2bf(v0.w);
    o.u[4]=f2bf(v1.x); o.u[5]=f2bf(v1.y); o.u[6]=f2bf(v1.z); o.u[7]=f2bf(v1.w);
    *(s16x8*)(xb + i) = o.v;
}

// ---------------------------------------------------------------------------
// Kernel 1: QKV projection.  y = x @ W^T.  Grid 512 = 8 col-tiles(32) x 64
// row-groups(256).  W LDS 50KB -> 2 blocks/CU.  bid%8 == rb%8 -> the 8 blocks
// sharing one x row-group land on one XCD (x L2 reuse).
// Qb (scaled 1/16) bf16 [16384][256], Kb bf16, Vt bf16 [b][d][s] via LDS transpose.
// ---------------------------------------------------------------------------
#define PWSTR 264

__global__ __launch_bounds__(256, 2) void proj_kernel(
    const unsigned short* __restrict__ xb, const float* __restrict__ Wq,
    const float* __restrict__ Wk, const float* __restrict__ Wv,
    unsigned short* __restrict__ Qb, unsigned short* __restrict__ Kb,
    unsigned short* __restrict__ Vt)
{
    __shared__ unsigned short Wl[3][32][PWSTR];  // 50688 B
    __shared__ unsigned short Vtr[32][72];       //  4608 B
    const int bid = blockIdx.x;
    const int ct  = bid >> 6;   // 0..7: 32 out-cols
    const int rb  = bid & 63;   // 256-row group
    const int t   = threadIdx.x;

    {   // stage 32x256 chunk of each W as bf16
        const float* Ws[3] = {Wq, Wk, Wv};
        const int o = t >> 3, seg = t & 7;
        for (int w = 0; w < 3; ++w) {
            const float* src = Ws[w] + (ct*32 + o)*256 + seg*32;
            #pragma unroll
            for (int i = 0; i < 8; ++i) {
                float4 v = *(const float4*)(src + i*4);
                ushort4 bv;
                bv.x = f2bf(v.x); bv.y = f2bf(v.y); bv.z = f2bf(v.z); bv.w = f2bf(v.w);
                *(ushort4*)&Wl[w][o][seg*32 + i*4] = bv;
            }
        }
    }
    __syncthreads();

    const int wave = t >> 6, lane = t & 63;
    const int g = lane >> 4, lr = lane & 15;

    for (int it = 0; it < 4; ++it) {
        const int rowblk = rb*256 + it*64;
        const int rowbase = rowblk + wave*16;
        s16x8 a[8];
        {
            const unsigned short* xr = xb + (size_t)(rowbase + lr)*256;
            #pragma unroll
            for (int c = 0; c < 8; ++c)
                a[c] = *(const s16x8*)(xr + c*32 + g*8);
        }
        f32x4 acc[3][2];
        #pragma unroll
        for (int w = 0; w < 3; ++w)
            #pragma unroll
            for (int cf = 0; cf < 2; ++cf)
                #pragma unroll
                for (int j = 0; j < 4; ++j) acc[w][cf][j] = 0.0f;

        #pragma unroll
        for (int w = 0; w < 3; ++w)
            #pragma unroll
            for (int cf = 0; cf < 2; ++cf)
                #pragma unroll
                for (int c = 0; c < 8; ++c) {
                    s16x8 bfr = *(const s16x8*)&Wl[w][cf*16 + lr][c*32 + g*8];
                    acc[w][cf] = __builtin_amdgcn_mfma_f32_16x16x32_bf16(a[c], bfr, acc[w][cf], 0, 0, 0);
                }

        #pragma unroll
        for (int cf = 0; cf < 2; ++cf) {
            const int col = ct*32 + cf*16 + lr;
            #pragma unroll
            for (int j = 0; j < 4; ++j) {
                const int srow = rowbase + g*4 + j;
                Qb[(size_t)srow*256 + col] = f2bf(acc[0][cf][j] * 0.0625f);  // fold 1/sqrt(256)
                Kb[(size_t)srow*256 + col] = f2bf(acc[1][cf][j]);
            }
        }
        __syncthreads();   // previous iteration's Vtr reads done
        #pragma unroll
        for (int cf = 0; cf < 2; ++cf) {
            ushort4 pv;
            pv.x = f2bf(acc[2][cf][0]); pv.y = f2bf(acc[2][cf][1]);
            pv.z = f2bf(acc[2][cf][2]); pv.w = f2bf(acc[2][cf][3]);
            *(ushort4*)&Vtr[cf*16 + lr][wave*16 + g*4] = pv;
        }
        __syncthreads();
        {
            const int colL = t >> 3, seg = t & 7;
            const int bb = rowblk >> 12, ss0 = rowblk & 4095;
            unsigned short* dst = Vt + ((size_t)(bb*256 + ct*32 + colL))*4096 + ss0 + seg*8;
            *(s16x8*)(dst) = *(const s16x8*)&Vtr[colL][seg*8];
        }
    }
}

// ---------------------------------------------------------------------------
// Kernel 2: flash attention, split-KV H=2, SWAPPED QK^T (mfma(K,Q) -> S^T).
// Each lane owns q-row lr: row-max/sum = 7 in-lane VALU + 2 shfl levels.
// P -> A-frag: 2 ds_write_b64 + 1 ds_read_b128 (vs 8+1 scattered before).
// Rescale factor crosses q-layouts via 64B per-wave LDS broadcast (rare).
// Grid 512 = 8 (b,h) XCD-pinned groups x 64 q-tiles; 2 blocks/CU.
// ---------------------------------------------------------------------------
#define KVB  32
#define NT   64          // 2048/32 per half
#define KSTR 264
#define VSTR 40
#define PSTR 40
#define RESCALE_THR 8.0f

__global__ __launch_bounds__(256, 2) void attn_kernel(
    const unsigned short* __restrict__ Qb, const unsigned short* __restrict__ Kb,
    const unsigned short* __restrict__ Vt, float* __restrict__ pacc0,
    float* __restrict__ pm, float* __restrict__ pl, float* __restrict__ out)
{
    __shared__ unsigned short Kl[2][KVB][KSTR];   // 33792 B
    __shared__ unsigned short Vl[2][EMB][VSTR];   // 40960 B
    __shared__ unsigned short Pl[4][16][PSTR];    //  5120 B (wave-private)
    __shared__ float All[4][16];                  //   256 B (wave-private)

    const int bid = blockIdx.x;
    const int grp = bid & 7;
    const int b = grp >> 1, h = grp & 1;
    const int qt  = bid >> 3;
    const int t   = threadIdx.x;
    const int wave = t >> 6, lane = t & 63;
    const int g = lane >> 4, lr = lane & 15;
    const int kv0 = h * 2048;
    const int rowbase = b*4096 + qt*64 + wave*16;

    // Q fragments (scaled by 1/16 already); same lane map serves as B-frag.
    s16x8 qa[8];
    {
        const unsigned short* qp = Qb + (size_t)(rowbase + lr)*256;
        #pragma unroll
        for (int c = 0; c < 8; ++c)
            qa[c] = *(const s16x8*)(qp + c*32 + g*8);
    }

    f32x4 acc[16];
    #pragma unroll
    for (int c = 0; c < 16; ++c)
        #pragma unroll
        for (int j = 0; j < 4; ++j) acc[c][j] = 0.0f;
    float m = -__builtin_inff(), l = 0.0f;   // per-lane state for q = lr

    const unsigned short* Kg = Kb + (size_t)b*4096*256;
    const unsigned short* Vg = Vt + (size_t)b*256*4096;

    s16x8 kreg[4], vreg[4];
    #pragma unroll
    for (int i = 0; i < 4; ++i) {
        const int idx = i*256 + t;
        const int kv = idx >> 5, e8 = idx & 31;     // K: 32 rows x 32 granules
        kreg[i] = *(const s16x8*)(Kg + (size_t)(kv0 + kv)*256 + e8*8);
        const int d = idx >> 2, seg = idx & 3;      // Vt: 256 rows x 4 granules
        vreg[i] = *(const s16x8*)(Vg + (size_t)d*4096 + kv0 + seg*8);
    }

    for (int kt = 0; kt < NT; ++kt) {
        const int buf = kt & 1;
        #pragma unroll
        for (int i = 0; i < 4; ++i) {
            const int idx = i*256 + t;
            const int kv = idx >> 5, e8 = idx & 31;
            *(s16x8*)&Kl[buf][kv][e8*8] = kreg[i];
            const int d = idx >> 2, seg = idx & 3;
            *(s16x8*)&Vl[buf][d][seg*8] = vreg[i];
        }
        if (kt + 1 < NT) {
            const int kvn = kv0 + (kt + 1) * KVB;
            #pragma unroll
            for (int i = 0; i < 4; ++i) {
                const int idx = i*256 + t;
                const int kv = idx >> 5, e8 = idx & 31;
                kreg[i] = *(const s16x8*)(Kg + (size_t)(kvn + kv)*256 + e8*8);
                const int d = idx >> 2, seg = idx & 3;
                vreg[i] = *(const s16x8*)(Vg + (size_t)d*4096 + kvn + seg*8);
            }
        }
        fence_barrier();

        // Swapped QK^T: C[kv][q], col = q = lr, row = kv = f*16 + g*4 + reg
        f32x4 sc[2];
        #pragma unroll
        for (int f = 0; f < 2; ++f)
            #pragma unroll
            for (int j = 0; j < 4; ++j) sc[f][j] = 0.0f;
        __builtin_amdgcn_s_setprio(1);
        #pragma unroll
        for (int f = 0; f < 2; ++f)
            #pragma unroll
            for (int c = 0; c < 8; ++c) {
                s16x8 kb = *(const s16x8*)&Kl[buf][f*16 + lr][c*32 + g*8];
                sc[f] = __builtin_amdgcn_mfma_f32_16x16x32_bf16(kb, qa[c], sc[f], 0, 0, 0);
            }
        __builtin_amdgcn_s_setprio(0);

        // Row reduce for q=lr: 7 in-lane max + 2 shfl levels
        float pmax = fmaxf(fmaxf(fmaxf(sc[0][0], sc[0][1]), fmaxf(sc[0][2], sc[0][3])),
                           fmaxf(fmaxf(sc[1][0], sc[1][1]), fmaxf(sc[1][2], sc[1][3])));
        pmax = fmaxf(pmax, __shfl_xor(pmax, 16));
        pmax = fmaxf(pmax, __shfl_xor(pmax, 32));

        if (!__all(pmax - m <= RESCALE_THR)) {
            const float mn = fmaxf(m, pmax);
            const float al = __builtin_amdgcn_exp2f((m - mn) * LOG2E);
            m = mn;
            l *= al;
            if (lane < 16) All[wave][lr] = al;        // q-layout bridge
            f32x4 al4 = *(const f32x4*)&All[wave][g*4];
            #pragma unroll
            for (int c = 0; c < 16; ++c)
                #pragma unroll
                for (int j = 0; j < 4; ++j) acc[c][j] *= al4[j];
        }

        float p[2][4];
        #pragma unroll
        for (int f = 0; f < 2; ++f)
            #pragma unroll
            for (int j = 0; j < 4; ++j)
                p[f][j] = __builtin_amdgcn_exp2f((sc[f][j] - m) * LOG2E);
        float ps = (p[0][0] + p[0][1]) + (p[0][2] + p[0][3])
                 + (p[1][0] + p[1][1]) + (p[1][2] + p[1][3]);
        ps += __shfl_xor(ps, 16);
        ps += __shfl_xor(ps, 32);
        l += ps;

        // P quartets -> A-fragment: row = lr, kv quartet f*16+g*4
        ushort4 q0, q1;
        q0.x = f2bf(p[0][0]); q0.y = f2bf(p[0][1]); q0.z = f2bf(p[0][2]); q0.w = f2bf(p[0][3]);
        q1.x = f2bf(p[1][0]); q1.y = f2bf(p[1][1]); q1.z = f2bf(p[1][2]); q1.w = f2bf(p[1][3]);
        *(ushort4*)&Pl[wave][lr][g*4]      = q0;
        *(ushort4*)&Pl[wave][lr][16 + g*4] = q1;
        s16x8 pa = *(const s16x8*)&Pl[wave][lr][g*8];

        __builtin_amdgcn_s_setprio(1);
        #pragma unroll
        for (int c = 0; c < 16; ++c) {
            s16x8 vb = *(const s16x8*)&Vl[buf][c*16 + lr][g*8];
            acc[c] = __builtin_amdgcn_mfma_f32_16x16x32_bf16(pa, vb, acc[c], 0, 0, 0);
        }
        __builtin_amdgcn_s_setprio(0);
    }

    // epilogue: unnormalized partials + (m,l)
    float* dst = h ? out : pacc0;
    #pragma unroll
    for (int c = 0; c < 16; ++c)
        #pragma unroll
        for (int j = 0; j < 4; ++j)
            dst[(size_t)(rowbase + g*4 + j)*256 + c*16 + lr] = acc[c][j];
    if (lane < 16) {
        pm[h*NROW + rowbase + lr] = m;
        pl[h*NROW + rowbase + lr] = l;
    }
}

// ---------------------------------------------------------------------------
// Kernel 3: combine the two KV-half partials.
// ---------------------------------------------------------------------------
__global__ __launch_bounds__(256, 4) void combine_kernel(
    const float* __restrict__ pacc0, const float* __restrict__ pm,
    const float* __restrict__ pl, float* __restrict__ out)
{
    const int idx = blockIdx.x*256 + threadIdx.x;
    const int row = idx >> 6, d4 = (idx & 63) << 2;
    const float m0 = pm[row], m1 = pm[NROW + row];
    const float l0 = pl[row], l1 = pl[NROW + row];
    const float M = fmaxf(m0, m1);
    const float w0 = __builtin_amdgcn_exp2f((m0 - M) * LOG2E);
    const float w1 = __builtin_amdgcn_exp2f((m1 - M) * LOG2E);
    const float r = 1.0f / (l0*w0 + l1*w1);
    const float4 a0 = *(const float4*)(pacc0 + (size_t)row*256 + d4);
    float4 a1 = *(const float4*)(out + (size_t)row*256 + d4);
    a1.x = (a0.x*w0 + a1.x*w1) * r;
    a1.y = (a0.y*w0 + a1.y*w1) * r;
    a1.z = (a0.z*w0 + a1.z*w1) * r;
    a1.w = (a0.w*w0 + a1.w*w1) * r;
    *(float4*)(out + (size_t)row*256 + d4) = a1;
}

// ---------------------------------------------------------------------------
extern "C" void kernel_launch(void* const* d_in, const int* in_sizes, int n_in,
                              void* d_out, int out_size, void* d_ws, size_t ws_size,
                              hipStream_t stream) {
    const float* x  = (const float*)d_in[0];
    const float* Wq = (const float*)d_in[1];
    const float* Wk = (const float*)d_in[2];
    const float* Wv = (const float*)d_in[3];

    unsigned short* Qb = (unsigned short*)d_ws;          // 8 MB
    unsigned short* Kb = Qb + (size_t)NROW*EMB;          // 8 MB
    unsigned short* Vt = Kb + (size_t)NROW*EMB;          // 8 MB, [b][d][s]
    float* pacc0 = (float*)(Vt + (size_t)NROW*EMB);      // 16 MB
    float* pm    = pacc0 + (size_t)NROW*EMB;             // 128 KB
    float* pl    = pm + 2*NROW;                          // 128 KB
    // xb (8 MB) aliases pacc0: dead after proj, pacc0 written only by attn.
    unsigned short* xb = (unsigned short*)pacc0;

    xcvt_kernel<<<2048, 256, 0, stream>>>(x, xb);
    proj_kernel<<<512, 256, 0, stream>>>(xb, Wq, Wk, Wv, Qb, Kb, Vt);
    attn_kernel<<<512, 256, 0, stream>>>(Qb, Kb, Vt, pacc0, pm, pl, (float*)d_out);
    combine_kernel<<<4096, 256, 0, stream>>>(pacc0, pm, pl, (float*)d_out);
}